// Round 9
// baseline (415.613 us; speedup 1.0000x reference)
//
#include <hip/hip_runtime.h>
#include <hip/hip_bf16.h>

// GCN: out = relu(gcnconv(relu(gcnconv(x,W1,b1)), W2, b2)) @ Wfc + bfc
// N=50000, E=800000, F0=100, F1=256, F2=128. All-fp32 value path (bf16 blows
// the ~6e-6 relative threshold — round-4 post-mortem; fp32 absmax itself
// varies 6e-5..5e-4 run-to-run via nondeterministic CSR order).
// Round 9: (a) pre-scaled gather tables xs = dinv*x and h2s = dinv*(a1@W2)
// (gemm2 epilogue) -> pull inner loops are pure gather+add, no per-edge dinv
// gather, half the shfls; (b) register-prefetch double-buffered GEMM staging.
// grid.sync forbidden (round-7: ~110 us/sync). Dispatch gap ~1.2 us (round-8).

#define F0 100
#define F1 256
#define F2 128

// ---------------- CSR construction ----------------

__global__ void zero_i32(int* p, int n) {
    int i = blockIdx.x * blockDim.x + threadIdx.x;
    if (i < n) p[i] = 0;
}

__global__ void deg_count_i(const int* __restrict__ dst, int* deg, int e) {
    int i = blockIdx.x * blockDim.x + threadIdx.x;
    if (i < e) atomicAdd(deg + dst[i], 1);
}

// per-block exclusive scan of deg + block sums; also emits dinv = rsqrt(deg+1)
__global__ __launch_bounds__(256) void scan1(const int* __restrict__ deg,
                                             int* __restrict__ excl,
                                             int* __restrict__ bsum,
                                             float* __restrict__ dinv, int n) {
    __shared__ int wsum[4];
    int i = blockIdx.x * 256 + threadIdx.x;
    int lane = threadIdx.x & 63, wid = threadIdx.x >> 6;
    int v = (i < n) ? deg[i] : 0;
    if (i < n) dinv[i] = rsqrtf((float)(v + 1));
    int s = v;
#pragma unroll
    for (int off = 1; off < 64; off <<= 1) {
        int t = __shfl_up(s, off, 64);
        if (lane >= off) s += t;
    }
    if (lane == 63) wsum[wid] = s;
    __syncthreads();
    int add = 0;
    for (int w = 0; w < wid; w++) add += wsum[w];
    if (i < n) excl[i] = add + s - v;
    if (threadIdx.x == 255) bsum[blockIdx.x] = add + s;
}

__global__ __launch_bounds__(256) void scan2(int* __restrict__ bsum, int nb,
                                             int* __restrict__ rowptr, int n) {
    __shared__ int wsum[4];
    int lane = threadIdx.x & 63, wid = threadIdx.x >> 6;
    int v = (threadIdx.x < nb) ? bsum[threadIdx.x] : 0;
    int s = v;
#pragma unroll
    for (int off = 1; off < 64; off <<= 1) {
        int t = __shfl_up(s, off, 64);
        if (lane >= off) s += t;
    }
    if (lane == 63) wsum[wid] = s;
    __syncthreads();
    int add = 0;
    for (int w = 0; w < wid; w++) add += wsum[w];
    if (threadIdx.x < nb) bsum[threadIdx.x] = add + s - v;
    if (threadIdx.x == 255) rowptr[n] = add + s;
}

__global__ void scan3(const int* __restrict__ excl, const int* __restrict__ bsum,
                      int* __restrict__ rowptr, int* __restrict__ cursor, int n) {
    int i = blockIdx.x * 256 + threadIdx.x;
    if (i < n) {
        int r = excl[i] + bsum[blockIdx.x];
        rowptr[i] = r;
        cursor[i] = r;
    }
}

__global__ void csr_fill(const int* __restrict__ src, const int* __restrict__ dst,
                         int* cursor, int* __restrict__ csr, int e) {
    int i = blockIdx.x * blockDim.x + threadIdx.x;
    if (i < e) {
        int pos = atomicAdd(cursor + dst[i], 1);
        csr[pos] = src[i];
    }
}

// xs = dinv[row] * x, row = float4-index / 25 (100 floats = 25 float4 exactly)
__global__ void scale_x(const float4* __restrict__ x4,
                        const float* __restrict__ dinv,
                        float4* __restrict__ xs4, int n25) {
    int i = blockIdx.x * blockDim.x + threadIdx.x;
    if (i < n25) {
        float d = dinv[i / 25];
        float4 v = x4[i];
        v.x *= d; v.y *= d; v.z *= d; v.w *= d;
        xs4[i] = v;
    }
}

// ---------------- pull-gather aggregation (pre-scaled tables) --------------

// agg[v][:] = dinv[v] * sum_{s in in(v) ∪ {v}} xs[s][:]
// One wave/node. Row = 25 float4. Lanes 0-24 even edges, 32-56 odd edges.
__global__ __launch_bounds__(256) void pull_f100(
        const float* __restrict__ xs, const int* __restrict__ rowptr,
        const int* __restrict__ csr, const float* __restrict__ dinv,
        float* __restrict__ agg, int n) {
    int wave = threadIdx.x >> 6, lane = threadIdx.x & 63;
    int v = blockIdx.x * 4 + wave;
    if (v >= n) return;
    int beg = rowptr[v], end = rowptr[v + 1];
    float dv = dinv[v];
    int half = lane >> 5, q = lane & 31;
    bool act = q < 25;
    float4 acc = {0.f, 0.f, 0.f, 0.f};
    if (half == 0 && act) acc = ((const float4*)(xs + (size_t)v * F0))[q];  // self

    for (int base = beg; base < end; base += 64) {
        int cnt = min(64, end - base);
        int sidx = (lane < cnt) ? csr[base + lane] : 0;
        int npf = cnt >> 1;
        int p = 0;
        for (; p + 4 <= npf; p += 4) {
            int s0 = __shfl(sidx, 2 * p + half, 64);
            int s1 = __shfl(sidx, 2 * p + 2 + half, 64);
            int s2 = __shfl(sidx, 2 * p + 4 + half, 64);
            int s3 = __shfl(sidx, 2 * p + 6 + half, 64);
            if (act) {
                float4 r0 = ((const float4*)(xs + (size_t)s0 * F0))[q];
                float4 r1 = ((const float4*)(xs + (size_t)s1 * F0))[q];
                float4 r2 = ((const float4*)(xs + (size_t)s2 * F0))[q];
                float4 r3 = ((const float4*)(xs + (size_t)s3 * F0))[q];
                acc.x += (r0.x + r1.x) + (r2.x + r3.x);
                acc.y += (r0.y + r1.y) + (r2.y + r3.y);
                acc.z += (r0.z + r1.z) + (r2.z + r3.z);
                acc.w += (r0.w + r1.w) + (r2.w + r3.w);
            }
        }
        for (; p < npf; p++) {
            int s0 = __shfl(sidx, 2 * p + half, 64);
            if (act) {
                float4 r0 = ((const float4*)(xs + (size_t)s0 * F0))[q];
                acc.x += r0.x; acc.y += r0.y; acc.z += r0.z; acc.w += r0.w;
            }
        }
        if (cnt & 1) {
            int sl = __shfl(sidx, cnt - 1, 64);
            if (half == 0 && act) {
                float4 r = ((const float4*)(xs + (size_t)sl * F0))[q];
                acc.x += r.x; acc.y += r.y; acc.z += r.z; acc.w += r.w;
            }
        }
    }
    float ox = __shfl_down(acc.x, 32, 64);
    float oy = __shfl_down(acc.y, 32, 64);
    float oz = __shfl_down(acc.z, 32, 64);
    float ow = __shfl_down(acc.w, 32, 64);
    if (half == 0 && act) {
        float4 r;
        r.x = dv * (acc.x + ox);
        r.y = dv * (acc.y + oy);
        r.z = dv * (acc.z + oz);
        r.w = dv * (acc.w + ow);
        ((float4*)(agg + (size_t)v * F0))[q] = r;
    }
}

// Fused layer-2 aggregation + bias + relu + final FC on pre-scaled h2s.
// out[v] = sum_f relu(dinv[v]*sum_{s∪{v}} h2s[s][f] + b2[f]) * Wfc[f] + bfc
__global__ __launch_bounds__(256) void pull_f128_fused(
        const float* __restrict__ h2s, const int* __restrict__ rowptr,
        const int* __restrict__ csr, const float* __restrict__ dinv,
        const float* __restrict__ b2, const float* __restrict__ Wfc,
        const float* __restrict__ bfc, float* __restrict__ out, int n) {
    int wave = threadIdx.x >> 6, lane = threadIdx.x & 63;
    int v = blockIdx.x * 4 + wave;
    if (v >= n) return;
    int beg = rowptr[v], end = rowptr[v + 1];
    float dv = dinv[v];
    int half = lane >> 5, q = lane & 31;
    float4 acc = {0.f, 0.f, 0.f, 0.f};
    if (half == 0) acc = ((const float4*)(h2s + (size_t)v * F2))[q];  // self

    for (int base = beg; base < end; base += 64) {
        int cnt = min(64, end - base);
        int sidx = (lane < cnt) ? csr[base + lane] : 0;
        int npf = cnt >> 1;
        int p = 0;
        for (; p + 4 <= npf; p += 4) {
            int s0 = __shfl(sidx, 2 * p + half, 64);
            int s1 = __shfl(sidx, 2 * p + 2 + half, 64);
            int s2 = __shfl(sidx, 2 * p + 4 + half, 64);
            int s3 = __shfl(sidx, 2 * p + 6 + half, 64);
            float4 r0 = ((const float4*)(h2s + (size_t)s0 * F2))[q];
            float4 r1 = ((const float4*)(h2s + (size_t)s1 * F2))[q];
            float4 r2 = ((const float4*)(h2s + (size_t)s2 * F2))[q];
            float4 r3 = ((const float4*)(h2s + (size_t)s3 * F2))[q];
            acc.x += (r0.x + r1.x) + (r2.x + r3.x);
            acc.y += (r0.y + r1.y) + (r2.y + r3.y);
            acc.z += (r0.z + r1.z) + (r2.z + r3.z);
            acc.w += (r0.w + r1.w) + (r2.w + r3.w);
        }
        for (; p < npf; p++) {
            int s0 = __shfl(sidx, 2 * p + half, 64);
            float4 r0 = ((const float4*)(h2s + (size_t)s0 * F2))[q];
            acc.x += r0.x; acc.y += r0.y; acc.z += r0.z; acc.w += r0.w;
        }
        if (cnt & 1) {
            int sl = __shfl(sidx, cnt - 1, 64);
            if (half == 0) {
                float4 r = ((const float4*)(h2s + (size_t)sl * F2))[q];
                acc.x += r.x; acc.y += r.y; acc.z += r.z; acc.w += r.w;
            }
        }
    }
    float ox = __shfl_down(acc.x, 32, 64);
    float oy = __shfl_down(acc.y, 32, 64);
    float oz = __shfl_down(acc.z, 32, 64);
    float ow = __shfl_down(acc.w, 32, 64);
    if (half == 0) {
        float4 b2v = ((const float4*)b2)[q];
        float4 wv = ((const float4*)Wfc)[q];
        float t0 = dv * (acc.x + ox);
        float t1 = dv * (acc.y + oy);
        float t2 = dv * (acc.z + oz);
        float t3 = dv * (acc.w + ow);
        float part = fmaxf(t0 + b2v.x, 0.f) * wv.x + fmaxf(t1 + b2v.y, 0.f) * wv.y +
                     fmaxf(t2 + b2v.z, 0.f) * wv.z + fmaxf(t3 + b2v.w, 0.f) * wv.w;
        part += __shfl_down(part, 16, 64);
        part += __shfl_down(part, 8, 64);
        part += __shfl_down(part, 4, 64);
        part += __shfl_down(part, 2, 64);
        part += __shfl_down(part, 1, 64);
        if (lane == 0) out[v] = part + bfc[0];
    }
}

// ---------------- dense transforms (fp32, 128x128, 8x8, prefetch dbuf) ----

// C = relu(A @ W + bias), A:[n,100], W:[100,256]. 5 K-chunks of 20.
__global__ __launch_bounds__(256) void gemm1_tiled(
        const float* __restrict__ A, const float* __restrict__ W,
        const float* __restrict__ bias, float* __restrict__ C, int n) {
    __shared__ float As[20 * 128];
    __shared__ float Bs[20 * 128];
    int tid = threadIdx.x;
    int r0 = blockIdx.x * 128, c0 = blockIdx.y * 128;
    int tc = tid & 15, tr = tid >> 4;
    float acc[8][8] = {};
    float4 pa[3], pb[3];
    const int NL = 640;  // float4s per operand tile

    auto ld = [&](int k0) {
#pragma unroll
        for (int j = 0; j < 3; j++) {
            int idx = tid + 256 * j;
            if (idx < NL) {
                int row = idx & 127, kq = idx >> 7;  // A: 128 rows x 5 kq
                int gr = r0 + row;
                if (gr >= n) gr = n - 1;
                pa[j] = *(const float4*)(A + (size_t)gr * F0 + k0 + 4 * kq);
                int k = idx >> 5, cq = idx & 31;     // B: 20 k x 32 cq
                pb[j] = *(const float4*)(W + (size_t)(k0 + k) * F1 + c0 + 4 * cq);
            }
        }
    };
    auto st = [&]() {
#pragma unroll
        for (int j = 0; j < 3; j++) {
            int idx = tid + 256 * j;
            if (idx < NL) {
                int row = idx & 127, kq = idx >> 7;
                As[(4 * kq + 0) * 128 + row] = pa[j].x;
                As[(4 * kq + 1) * 128 + row] = pa[j].y;
                As[(4 * kq + 2) * 128 + row] = pa[j].z;
                As[(4 * kq + 3) * 128 + row] = pa[j].w;
                int k = idx >> 5, cq = idx & 31;
                *(float4*)(Bs + k * 128 + 4 * cq) = pb[j];
            }
        }
    };

    ld(0);
    for (int c = 0; c < 5; c++) {
        st();
        __syncthreads();
        if (c < 4) ld(20 * (c + 1));  // prefetch overlaps compute below
#pragma unroll 5
        for (int k = 0; k < 20; k++) {
            float4 a0 = *(const float4*)(As + k * 128 + 4 * tr);
            float4 a1 = *(const float4*)(As + k * 128 + 64 + 4 * tr);
            float4 b0 = *(const float4*)(Bs + k * 128 + 4 * tc);
            float4 b1 = *(const float4*)(Bs + k * 128 + 64 + 4 * tc);
            float av[8] = {a0.x, a0.y, a0.z, a0.w, a1.x, a1.y, a1.z, a1.w};
            float bv[8] = {b0.x, b0.y, b0.z, b0.w, b1.x, b1.y, b1.z, b1.w};
#pragma unroll
            for (int i = 0; i < 8; i++)
#pragma unroll
                for (int j = 0; j < 8; j++) acc[i][j] += av[i] * bv[j];
        }
        __syncthreads();
    }
    float4 bb0 = *(const float4*)(bias + c0 + 4 * tc);
    float4 bb1 = *(const float4*)(bias + c0 + 64 + 4 * tc);
    float bv[8] = {bb0.x, bb0.y, bb0.z, bb0.w, bb1.x, bb1.y, bb1.z, bb1.w};
#pragma unroll
    for (int i = 0; i < 8; i++) {
        int row = (i < 4) ? (4 * tr + i) : (64 + 4 * tr + i - 4);
        int gr = r0 + row;
        if (gr < n) {
            float4 o0, o1;
            o0.x = fmaxf(acc[i][0] + bv[0], 0.f);
            o0.y = fmaxf(acc[i][1] + bv[1], 0.f);
            o0.z = fmaxf(acc[i][2] + bv[2], 0.f);
            o0.w = fmaxf(acc[i][3] + bv[3], 0.f);
            o1.x = fmaxf(acc[i][4] + bv[4], 0.f);
            o1.y = fmaxf(acc[i][5] + bv[5], 0.f);
            o1.z = fmaxf(acc[i][6] + bv[6], 0.f);
            o1.w = fmaxf(acc[i][7] + bv[7], 0.f);
            *(float4*)(C + (size_t)gr * F1 + c0 + 4 * tc) = o0;
            *(float4*)(C + (size_t)gr * F1 + c0 + 64 + 4 * tc) = o1;
        }
    }
}

// h2s = dinv[row] * (A @ W), A:[n,256], W:[256,128]. 8 K-chunks of 32.
__global__ __launch_bounds__(256) void gemm2_tiled(
        const float* __restrict__ A, const float* __restrict__ W,
        const float* __restrict__ dinv, float* __restrict__ C, int n) {
    __shared__ float As[32 * 128];
    __shared__ float Bs[32 * 128];
    int tid = threadIdx.x;
    int r0 = blockIdx.x * 128;
    int tc = tid & 15, tr = tid >> 4;
    float acc[8][8] = {};
    float4 pa[4], pb[4];

    auto ld = [&](int k0) {
#pragma unroll
        for (int j = 0; j < 4; j++) {
            int idx = tid + 256 * j;           // 1024 float4s each
            int row = idx & 127, kq = idx >> 7;  // A: 128 rows x 8 kq
            int gr = r0 + row;
            if (gr >= n) gr = n - 1;
            pa[j] = *(const float4*)(A + (size_t)gr * F1 + k0 + 4 * kq);
            int k = idx >> 5, cq = idx & 31;     // B: 32 k x 32 cq
            pb[j] = *(const float4*)(W + (size_t)(k0 + k) * F2 + 4 * cq);
        }
    };
    auto st = [&]() {
#pragma unroll
        for (int j = 0; j < 4; j++) {
            int idx = tid + 256 * j;
            int row = idx & 127, kq = idx >> 7;
            As[(4 * kq + 0) * 128 + row] = pa[j].x;
            As[(4 * kq + 1) * 128 + row] = pa[j].y;
            As[(4 * kq + 2) * 128 + row] = pa[j].z;
            As[(4 * kq + 3) * 128 + row] = pa[j].w;
            int k = idx >> 5, cq = idx & 31;
            *(float4*)(Bs + k * 128 + 4 * cq) = pb[j];
        }
    };

    ld(0);
    for (int c = 0; c < 8; c++) {
        st();
        __syncthreads();
        if (c < 7) ld(32 * (c + 1));
#pragma unroll 4
        for (int k = 0; k < 32; k++) {
            float4 a0 = *(const float4*)(As + k * 128 + 4 * tr);
            float4 a1 = *(const float4*)(As + k * 128 + 64 + 4 * tr);
            float4 b0 = *(const float4*)(Bs + k * 128 + 4 * tc);
            float4 b1 = *(const float4*)(Bs + k * 128 + 64 + 4 * tc);
            float av[8] = {a0.x, a0.y, a0.z, a0.w, a1.x, a1.y, a1.z, a1.w};
            float bv[8] = {b0.x, b0.y, b0.z, b0.w, b1.x, b1.y, b1.z, b1.w};
#pragma unroll
            for (int i = 0; i < 8; i++)
#pragma unroll
                for (int j = 0; j < 8; j++) acc[i][j] += av[i] * bv[j];
        }
        __syncthreads();
    }
#pragma unroll
    for (int i = 0; i < 8; i++) {
        int row = (i < 4) ? (4 * tr + i) : (64 + 4 * tr + i - 4);
        int gr = r0 + row;
        if (gr < n) {
            float d = dinv[gr];
            float4 o0 = {acc[i][0] * d, acc[i][1] * d, acc[i][2] * d, acc[i][3] * d};
            float4 o1 = {acc[i][4] * d, acc[i][5] * d, acc[i][6] * d, acc[i][7] * d};
            *(float4*)(C + (size_t)gr * F2 + 4 * tc) = o0;
            *(float4*)(C + (size_t)gr * F2 + 64 + 4 * tc) = o1;
        }
    }
}

// ---------------- launch ----------------

static inline size_t align16(size_t x) { return (x + 3) & ~(size_t)3; }  // in 4B elems

extern "C" void kernel_launch(void* const* d_in, const int* in_sizes, int n_in,
                              void* d_out, int out_size, void* d_ws, size_t ws_size,
                              hipStream_t stream) {
    const float* x   = (const float*)d_in[0];
    const int*   ei  = (const int*)d_in[1];
    const float* W1  = (const float*)d_in[2];
    const float* b1  = (const float*)d_in[3];
    const float* W2  = (const float*)d_in[4];
    const float* b2  = (const float*)d_in[5];
    const float* Wfc = (const float*)d_in[6];
    const float* bfc = (const float*)d_in[7];
    float* out = (float*)d_out;

    const int n = in_sizes[0] / F0;   // 50000
    const int e = in_sizes[1] / 2;    // 800000
    const int* src = ei;
    const int* dst = ei + e;

    // workspace layout (4-byte elements, each region 16B-aligned)
    char* wsb = (char*)d_ws;
    size_t off = 0;
    int* deg    = (int*)(wsb + 4 * off); off = align16(off + n);
    int* excl   = (int*)(wsb + 4 * off); off = align16(off + n);
    int* bsum   = (int*)(wsb + 4 * off); off = align16(off + 256);
    int* rowptr = (int*)(wsb + 4 * off); off = align16(off + n + 1);
    int* cursor = (int*)(wsb + 4 * off); off = align16(off + n);
    int* csr    = (int*)(wsb + 4 * off); off = align16(off + e);
    float* dinv = (float*)(wsb + 4 * off); off = align16(off + n);
    float* xs   = (float*)(wsb + 4 * off); off = align16(off + (size_t)n * F0);
    float* aggX = (float*)(wsb + 4 * off); off = align16(off + (size_t)n * F0);
    float* a1   = (float*)(wsb + 4 * off); off = align16(off + (size_t)n * F1);
    float* h2s  = (float*)(wsb + 4 * off); off = align16(off + (size_t)n * F2);

    const int B = 256;
    const int nb = (n + B - 1) / B;        // 196 (<= 256)
    const int rblocks = (n + 127) / 128;

    // CSR build + scaled-x table
    zero_i32<<<nb, B, 0, stream>>>(deg, n);
    deg_count_i<<<(e + B - 1) / B, B, 0, stream>>>(dst, deg, e);
    scan1<<<nb, B, 0, stream>>>(deg, excl, bsum, dinv, n);
    scale_x<<<((n * 25) + B - 1) / B, B, 0, stream>>>(
        (const float4*)x, dinv, (float4*)xs, n * 25);
    scan2<<<1, B, 0, stream>>>(bsum, nb, rowptr, n);
    scan3<<<nb, B, 0, stream>>>(excl, bsum, rowptr, cursor, n);
    csr_fill<<<(e + B - 1) / B, B, 0, stream>>>(src, dst, cursor, csr, e);

    // layer 1: pull-aggregate xs, then tiled GEMM + bias + relu
    pull_f100<<<(n + 3) / 4, 256, 0, stream>>>(xs, rowptr, csr, dinv, aggX, n);
    gemm1_tiled<<<dim3(rblocks, F1 / 128), 256, 0, stream>>>(aggX, W1, b1, a1, n);

    // layer 2: tiled GEMM -> pre-scaled h2s, then fused pull + bias+relu+FC
    gemm2_tiled<<<rblocks, 256, 0, stream>>>(a1, W2, dinv, h2s, n);
    pull_f128_fused<<<(n + 3) / 4, 256, 0, stream>>>(h2s, rowptr, csr, dinv,
                                                     b2, Wfc, bfc, out, n);
}

// Round 10
// 387.298 us; speedup vs baseline: 1.0731x; 1.0731x over previous
//
#include <hip/hip_runtime.h>
#include <hip/hip_bf16.h>

// GCN: out = relu(gcnconv(relu(gcnconv(x,W1,b1)), W2, b2)) @ Wfc + bfc
// N=50000, E=800000, F0=100, F1=256, F2=128. All-fp32 value path (bf16 blows
// the ~6e-6 relative threshold — round-4 post-mortem).
// Round 10: keep round-9's pre-scaled tables (xs = dinv*x, h2s = dinv*(a1@W2))
// but REVERT the GEMM register-prefetch (round-9: +32 VGPR pushed gemm2 over
// the 128-VGPR cliff -> 1 wave/SIMD, 13% occupancy, 75 us). Round-6 direct
// LDS staging restored. grid.sync forbidden (round-7). Gap/dispatch ~1.2 us.

#define F0 100
#define F1 256
#define F2 128

// ---------------- CSR construction ----------------

__global__ void zero_i32(int* p, int n) {
    int i = blockIdx.x * blockDim.x + threadIdx.x;
    if (i < n) p[i] = 0;
}

__global__ void deg_count_i(const int* __restrict__ dst, int* deg, int e) {
    int i = blockIdx.x * blockDim.x + threadIdx.x;
    if (i < e) atomicAdd(deg + dst[i], 1);
}

// per-block exclusive scan of deg + block sums; also emits dinv = rsqrt(deg+1)
__global__ __launch_bounds__(256) void scan1(const int* __restrict__ deg,
                                             int* __restrict__ excl,
                                             int* __restrict__ bsum,
                                             float* __restrict__ dinv, int n) {
    __shared__ int wsum[4];
    int i = blockIdx.x * 256 + threadIdx.x;
    int lane = threadIdx.x & 63, wid = threadIdx.x >> 6;
    int v = (i < n) ? deg[i] : 0;
    if (i < n) dinv[i] = rsqrtf((float)(v + 1));
    int s = v;
#pragma unroll
    for (int off = 1; off < 64; off <<= 1) {
        int t = __shfl_up(s, off, 64);
        if (lane >= off) s += t;
    }
    if (lane == 63) wsum[wid] = s;
    __syncthreads();
    int add = 0;
    for (int w = 0; w < wid; w++) add += wsum[w];
    if (i < n) excl[i] = add + s - v;
    if (threadIdx.x == 255) bsum[blockIdx.x] = add + s;
}

__global__ __launch_bounds__(256) void scan2(int* __restrict__ bsum, int nb,
                                             int* __restrict__ rowptr, int n) {
    __shared__ int wsum[4];
    int lane = threadIdx.x & 63, wid = threadIdx.x >> 6;
    int v = (threadIdx.x < nb) ? bsum[threadIdx.x] : 0;
    int s = v;
#pragma unroll
    for (int off = 1; off < 64; off <<= 1) {
        int t = __shfl_up(s, off, 64);
        if (lane >= off) s += t;
    }
    if (lane == 63) wsum[wid] = s;
    __syncthreads();
    int add = 0;
    for (int w = 0; w < wid; w++) add += wsum[w];
    if (threadIdx.x < nb) bsum[threadIdx.x] = add + s - v;
    if (threadIdx.x == 255) rowptr[n] = add + s;
}

__global__ void scan3(const int* __restrict__ excl, const int* __restrict__ bsum,
                      int* __restrict__ rowptr, int* __restrict__ cursor, int n) {
    int i = blockIdx.x * 256 + threadIdx.x;
    if (i < n) {
        int r = excl[i] + bsum[blockIdx.x];
        rowptr[i] = r;
        cursor[i] = r;
    }
}

__global__ void csr_fill(const int* __restrict__ src, const int* __restrict__ dst,
                         int* cursor, int* __restrict__ csr, int e) {
    int i = blockIdx.x * blockDim.x + threadIdx.x;
    if (i < e) {
        int pos = atomicAdd(cursor + dst[i], 1);
        csr[pos] = src[i];
    }
}

// xs = dinv[row] * x, row = float4-index / 25 (100 floats = 25 float4)
__global__ void scale_x(const float4* __restrict__ x4,
                        const float* __restrict__ dinv,
                        float4* __restrict__ xs4, int n25) {
    int i = blockIdx.x * blockDim.x + threadIdx.x;
    if (i < n25) {
        float d = dinv[i / 25];
        float4 v = x4[i];
        v.x *= d; v.y *= d; v.z *= d; v.w *= d;
        xs4[i] = v;
    }
}

// ---------------- pull-gather aggregation (pre-scaled tables) --------------

// agg[v][:] = dinv[v] * sum_{s in in(v) ∪ {v}} xs[s][:]
// One wave/node. Row = 25 float4. Lanes 0-24 even edges, 32-56 odd edges.
__global__ __launch_bounds__(256) void pull_f100(
        const float* __restrict__ xs, const int* __restrict__ rowptr,
        const int* __restrict__ csr, const float* __restrict__ dinv,
        float* __restrict__ agg, int n) {
    int wave = threadIdx.x >> 6, lane = threadIdx.x & 63;
    int v = blockIdx.x * 4 + wave;
    if (v >= n) return;
    int beg = rowptr[v], end = rowptr[v + 1];
    float dv = dinv[v];
    int half = lane >> 5, q = lane & 31;
    bool act = q < 25;
    float4 acc = {0.f, 0.f, 0.f, 0.f};
    if (half == 0 && act) acc = ((const float4*)(xs + (size_t)v * F0))[q];  // self

    for (int base = beg; base < end; base += 64) {
        int cnt = min(64, end - base);
        int sidx = (lane < cnt) ? csr[base + lane] : 0;
        int npf = cnt >> 1;
        int p = 0;
        for (; p + 4 <= npf; p += 4) {
            int s0 = __shfl(sidx, 2 * p + half, 64);
            int s1 = __shfl(sidx, 2 * p + 2 + half, 64);
            int s2 = __shfl(sidx, 2 * p + 4 + half, 64);
            int s3 = __shfl(sidx, 2 * p + 6 + half, 64);
            if (act) {
                float4 r0 = ((const float4*)(xs + (size_t)s0 * F0))[q];
                float4 r1 = ((const float4*)(xs + (size_t)s1 * F0))[q];
                float4 r2 = ((const float4*)(xs + (size_t)s2 * F0))[q];
                float4 r3 = ((const float4*)(xs + (size_t)s3 * F0))[q];
                acc.x += (r0.x + r1.x) + (r2.x + r3.x);
                acc.y += (r0.y + r1.y) + (r2.y + r3.y);
                acc.z += (r0.z + r1.z) + (r2.z + r3.z);
                acc.w += (r0.w + r1.w) + (r2.w + r3.w);
            }
        }
        for (; p < npf; p++) {
            int s0 = __shfl(sidx, 2 * p + half, 64);
            if (act) {
                float4 r0 = ((const float4*)(xs + (size_t)s0 * F0))[q];
                acc.x += r0.x; acc.y += r0.y; acc.z += r0.z; acc.w += r0.w;
            }
        }
        if (cnt & 1) {
            int sl = __shfl(sidx, cnt - 1, 64);
            if (half == 0 && act) {
                float4 r = ((const float4*)(xs + (size_t)sl * F0))[q];
                acc.x += r.x; acc.y += r.y; acc.z += r.z; acc.w += r.w;
            }
        }
    }
    float ox = __shfl_down(acc.x, 32, 64);
    float oy = __shfl_down(acc.y, 32, 64);
    float oz = __shfl_down(acc.z, 32, 64);
    float ow = __shfl_down(acc.w, 32, 64);
    if (half == 0 && act) {
        float4 r;
        r.x = dv * (acc.x + ox);
        r.y = dv * (acc.y + oy);
        r.z = dv * (acc.z + oz);
        r.w = dv * (acc.w + ow);
        ((float4*)(agg + (size_t)v * F0))[q] = r;
    }
}

// Fused layer-2 aggregation + bias + relu + final FC on pre-scaled h2s.
__global__ __launch_bounds__(256) void pull_f128_fused(
        const float* __restrict__ h2s, const int* __restrict__ rowptr,
        const int* __restrict__ csr, const float* __restrict__ dinv,
        const float* __restrict__ b2, const float* __restrict__ Wfc,
        const float* __restrict__ bfc, float* __restrict__ out, int n) {
    int wave = threadIdx.x >> 6, lane = threadIdx.x & 63;
    int v = blockIdx.x * 4 + wave;
    if (v >= n) return;
    int beg = rowptr[v], end = rowptr[v + 1];
    float dv = dinv[v];
    int half = lane >> 5, q = lane & 31;
    float4 acc = {0.f, 0.f, 0.f, 0.f};
    if (half == 0) acc = ((const float4*)(h2s + (size_t)v * F2))[q];  // self

    for (int base = beg; base < end; base += 64) {
        int cnt = min(64, end - base);
        int sidx = (lane < cnt) ? csr[base + lane] : 0;
        int npf = cnt >> 1;
        int p = 0;
        for (; p + 4 <= npf; p += 4) {
            int s0 = __shfl(sidx, 2 * p + half, 64);
            int s1 = __shfl(sidx, 2 * p + 2 + half, 64);
            int s2 = __shfl(sidx, 2 * p + 4 + half, 64);
            int s3 = __shfl(sidx, 2 * p + 6 + half, 64);
            float4 r0 = ((const float4*)(h2s + (size_t)s0 * F2))[q];
            float4 r1 = ((const float4*)(h2s + (size_t)s1 * F2))[q];
            float4 r2 = ((const float4*)(h2s + (size_t)s2 * F2))[q];
            float4 r3 = ((const float4*)(h2s + (size_t)s3 * F2))[q];
            acc.x += (r0.x + r1.x) + (r2.x + r3.x);
            acc.y += (r0.y + r1.y) + (r2.y + r3.y);
            acc.z += (r0.z + r1.z) + (r2.z + r3.z);
            acc.w += (r0.w + r1.w) + (r2.w + r3.w);
        }
        for (; p < npf; p++) {
            int s0 = __shfl(sidx, 2 * p + half, 64);
            float4 r0 = ((const float4*)(h2s + (size_t)s0 * F2))[q];
            acc.x += r0.x; acc.y += r0.y; acc.z += r0.z; acc.w += r0.w;
        }
        if (cnt & 1) {
            int sl = __shfl(sidx, cnt - 1, 64);
            if (half == 0) {
                float4 r = ((const float4*)(h2s + (size_t)sl * F2))[q];
                acc.x += r.x; acc.y += r.y; acc.z += r.z; acc.w += r.w;
            }
        }
    }
    float ox = __shfl_down(acc.x, 32, 64);
    float oy = __shfl_down(acc.y, 32, 64);
    float oz = __shfl_down(acc.z, 32, 64);
    float ow = __shfl_down(acc.w, 32, 64);
    if (half == 0) {
        float4 b2v = ((const float4*)b2)[q];
        float4 wv = ((const float4*)Wfc)[q];
        float t0 = dv * (acc.x + ox);
        float t1 = dv * (acc.y + oy);
        float t2 = dv * (acc.z + oz);
        float t3 = dv * (acc.w + ow);
        float part = fmaxf(t0 + b2v.x, 0.f) * wv.x + fmaxf(t1 + b2v.y, 0.f) * wv.y +
                     fmaxf(t2 + b2v.z, 0.f) * wv.z + fmaxf(t3 + b2v.w, 0.f) * wv.w;
        part += __shfl_down(part, 16, 64);
        part += __shfl_down(part, 8, 64);
        part += __shfl_down(part, 4, 64);
        part += __shfl_down(part, 2, 64);
        part += __shfl_down(part, 1, 64);
        if (lane == 0) out[v] = part + bfc[0];
    }
}

// ---------------- dense transforms (fp32, 128x128 tile, 8x8 micro) --------
// Direct LDS staging (NO register prefetch — round-9 occupancy cliff).

// C = relu(A @ W + bias), A:[n,100], W:[100,256]. K chunked by 20.
__global__ __launch_bounds__(256) void gemm1_tiled(
        const float* __restrict__ A, const float* __restrict__ W,
        const float* __restrict__ bias, float* __restrict__ C, int n) {
    __shared__ float As[20 * 128];
    __shared__ float Bs[20 * 128];
    int tid = threadIdx.x;
    int r0 = blockIdx.x * 128;
    int c0 = blockIdx.y * 128;
    int tc = tid & 15, tr = tid >> 4;
    float acc[8][8] = {};

    for (int k0 = 0; k0 < F0; k0 += 20) {
        if (k0) __syncthreads();
        for (int idx = tid; idx < 128 * 5; idx += 256) {
            int row = idx & 127, kq = idx >> 7;
            int gr = r0 + row;
            if (gr >= n) gr = n - 1;
            float4 v = *(const float4*)(A + (size_t)gr * F0 + k0 + 4 * kq);
            As[(4 * kq + 0) * 128 + row] = v.x;
            As[(4 * kq + 1) * 128 + row] = v.y;
            As[(4 * kq + 2) * 128 + row] = v.z;
            As[(4 * kq + 3) * 128 + row] = v.w;
        }
        for (int idx = tid; idx < 20 * 32; idx += 256) {
            int k = idx >> 5, cq = idx & 31;
            *(float4*)(Bs + k * 128 + 4 * cq) =
                *(const float4*)(W + (size_t)(k0 + k) * F1 + c0 + 4 * cq);
        }
        __syncthreads();
#pragma unroll 5
        for (int k = 0; k < 20; k++) {
            float4 a0 = *(const float4*)(As + k * 128 + 4 * tr);
            float4 a1 = *(const float4*)(As + k * 128 + 64 + 4 * tr);
            float4 b0 = *(const float4*)(Bs + k * 128 + 4 * tc);
            float4 b1 = *(const float4*)(Bs + k * 128 + 64 + 4 * tc);
            float av[8] = {a0.x, a0.y, a0.z, a0.w, a1.x, a1.y, a1.z, a1.w};
            float bv[8] = {b0.x, b0.y, b0.z, b0.w, b1.x, b1.y, b1.z, b1.w};
#pragma unroll
            for (int i = 0; i < 8; i++)
#pragma unroll
                for (int j = 0; j < 8; j++) acc[i][j] += av[i] * bv[j];
        }
    }
    float4 bb0 = *(const float4*)(bias + c0 + 4 * tc);
    float4 bb1 = *(const float4*)(bias + c0 + 64 + 4 * tc);
    float bv[8] = {bb0.x, bb0.y, bb0.z, bb0.w, bb1.x, bb1.y, bb1.z, bb1.w};
#pragma unroll
    for (int i = 0; i < 8; i++) {
        int row = (i < 4) ? (4 * tr + i) : (64 + 4 * tr + i - 4);
        int gr = r0 + row;
        if (gr < n) {
            float4 o0, o1;
            o0.x = fmaxf(acc[i][0] + bv[0], 0.f);
            o0.y = fmaxf(acc[i][1] + bv[1], 0.f);
            o0.z = fmaxf(acc[i][2] + bv[2], 0.f);
            o0.w = fmaxf(acc[i][3] + bv[3], 0.f);
            o1.x = fmaxf(acc[i][4] + bv[4], 0.f);
            o1.y = fmaxf(acc[i][5] + bv[5], 0.f);
            o1.z = fmaxf(acc[i][6] + bv[6], 0.f);
            o1.w = fmaxf(acc[i][7] + bv[7], 0.f);
            *(float4*)(C + (size_t)gr * F1 + c0 + 4 * tc) = o0;
            *(float4*)(C + (size_t)gr * F1 + c0 + 64 + 4 * tc) = o1;
        }
    }
}

// h2s = dinv[row] * (A @ W), A:[n,256], W:[256,128]. 128 rows x full F2, K by 32.
__global__ __launch_bounds__(256) void gemm2_tiled(
        const float* __restrict__ A, const float* __restrict__ W,
        const float* __restrict__ dinv, float* __restrict__ C, int n) {
    __shared__ float As[32 * 128];
    __shared__ float Bs[32 * 128];
    int tid = threadIdx.x;
    int r0 = blockIdx.x * 128;
    int tc = tid & 15, tr = tid >> 4;
    float acc[8][8] = {};

    for (int k0 = 0; k0 < F1; k0 += 32) {
        if (k0) __syncthreads();
        for (int idx = tid; idx < 128 * 8; idx += 256) {
            int row = idx & 127, kq = idx >> 7;
            int gr = r0 + row;
            if (gr >= n) gr = n - 1;
            float4 v = *(const float4*)(A + (size_t)gr * F1 + k0 + 4 * kq);
            As[(4 * kq + 0) * 128 + row] = v.x;
            As[(4 * kq + 1) * 128 + row] = v.y;
            As[(4 * kq + 2) * 128 + row] = v.z;
            As[(4 * kq + 3) * 128 + row] = v.w;
        }
        for (int idx = tid; idx < 32 * 32; idx += 256) {
            int k = idx >> 5, cq = idx & 31;
            *(float4*)(Bs + k * 128 + 4 * cq) =
                *(const float4*)(W + (size_t)(k0 + k) * F2 + 4 * cq);
        }
        __syncthreads();
#pragma unroll 4
        for (int k = 0; k < 32; k++) {
            float4 a0 = *(const float4*)(As + k * 128 + 4 * tr);
            float4 a1 = *(const float4*)(As + k * 128 + 64 + 4 * tr);
            float4 b0 = *(const float4*)(Bs + k * 128 + 4 * tc);
            float4 b1 = *(const float4*)(Bs + k * 128 + 64 + 4 * tc);
            float av[8] = {a0.x, a0.y, a0.z, a0.w, a1.x, a1.y, a1.z, a1.w};
            float bv[8] = {b0.x, b0.y, b0.z, b0.w, b1.x, b1.y, b1.z, b1.w};
#pragma unroll
            for (int i = 0; i < 8; i++)
#pragma unroll
                for (int j = 0; j < 8; j++) acc[i][j] += av[i] * bv[j];
        }
    }
#pragma unroll
    for (int i = 0; i < 8; i++) {
        int row = (i < 4) ? (4 * tr + i) : (64 + 4 * tr + i - 4);
        int gr = r0 + row;
        if (gr < n) {
            float d = dinv[gr];
            float4 o0 = {acc[i][0] * d, acc[i][1] * d, acc[i][2] * d, acc[i][3] * d};
            float4 o1 = {acc[i][4] * d, acc[i][5] * d, acc[i][6] * d, acc[i][7] * d};
            *(float4*)(C + (size_t)gr * F2 + 4 * tc) = o0;
            *(float4*)(C + (size_t)gr * F2 + 64 + 4 * tc) = o1;
        }
    }
}

// ---------------- launch ----------------

static inline size_t align16(size_t x) { return (x + 3) & ~(size_t)3; }  // in 4B elems

extern "C" void kernel_launch(void* const* d_in, const int* in_sizes, int n_in,
                              void* d_out, int out_size, void* d_ws, size_t ws_size,
                              hipStream_t stream) {
    const float* x   = (const float*)d_in[0];
    const int*   ei  = (const int*)d_in[1];
    const float* W1  = (const float*)d_in[2];
    const float* b1  = (const float*)d_in[3];
    const float* W2  = (const float*)d_in[4];
    const float* b2  = (const float*)d_in[5];
    const float* Wfc = (const float*)d_in[6];
    const float* bfc = (const float*)d_in[7];
    float* out = (float*)d_out;

    const int n = in_sizes[0] / F0;   // 50000
    const int e = in_sizes[1] / 2;    // 800000
    const int* src = ei;
    const int* dst = ei + e;

    // workspace layout (4-byte elements, each region 16B-aligned)
    char* wsb = (char*)d_ws;
    size_t off = 0;
    int* deg    = (int*)(wsb + 4 * off); off = align16(off + n);
    int* excl   = (int*)(wsb + 4 * off); off = align16(off + n);
    int* bsum   = (int*)(wsb + 4 * off); off = align16(off + 256);
    int* rowptr = (int*)(wsb + 4 * off); off = align16(off + n + 1);
    int* cursor = (int*)(wsb + 4 * off); off = align16(off + n);
    int* csr    = (int*)(wsb + 4 * off); off = align16(off + e);
    float* dinv = (float*)(wsb + 4 * off); off = align16(off + n);
    float* xs   = (float*)(wsb + 4 * off); off = align16(off + (size_t)n * F0);
    float* aggX = (float*)(wsb + 4 * off); off = align16(off + (size_t)n * F0);
    float* a1   = (float*)(wsb + 4 * off); off = align16(off + (size_t)n * F1);
    float* h2s  = (float*)(wsb + 4 * off); off = align16(off + (size_t)n * F2);

    const int B = 256;
    const int nb = (n + B - 1) / B;        // 196 (<= 256)
    const int rblocks = (n + 127) / 128;

    // CSR build + scaled-x table
    zero_i32<<<nb, B, 0, stream>>>(deg, n);
    deg_count_i<<<(e + B - 1) / B, B, 0, stream>>>(dst, deg, e);
    scan1<<<nb, B, 0, stream>>>(deg, excl, bsum, dinv, n);
    scale_x<<<((n * 25) + B - 1) / B, B, 0, stream>>>(
        (const float4*)x, dinv, (float4*)xs, n * 25);
    scan2<<<1, B, 0, stream>>>(bsum, nb, rowptr, n);
    scan3<<<nb, B, 0, stream>>>(excl, bsum, rowptr, cursor, n);
    csr_fill<<<(e + B - 1) / B, B, 0, stream>>>(src, dst, cursor, csr, e);

    // layer 1: pull-aggregate xs, then tiled GEMM + bias + relu
    pull_f100<<<(n + 3) / 4, 256, 0, stream>>>(xs, rowptr, csr, dinv, aggX, n);
    gemm1_tiled<<<dim3(rblocks, F1 / 128), 256, 0, stream>>>(aggX, W1, b1, a1, n);

    // layer 2: tiled GEMM -> pre-scaled h2s, then fused pull + bias+relu+FC
    gemm2_tiled<<<rblocks, 256, 0, stream>>>(a1, W2, dinv, h2s, n);
    pull_f128_fused<<<(n + 3) / 4, 256, 0, stream>>>(h2s, rowptr, csr, dinv,
                                                     b2, Wfc, bfc, out, n);
}